// Round 19
// baseline (238.979 us; speedup 1.0000x reference)
//
#include <hip/hip_runtime.h>
#include <hip/hip_bf16.h>
#include <math.h>

#define NTOK 2304   // N = 48*48
#define DIMC 256

typedef __attribute__((ext_vector_type(8))) short short8;
typedef __attribute__((ext_vector_type(4))) float f32x4;

__device__ __forceinline__ unsigned short f2bf(float f) {
  unsigned u = __float_as_uint(f);
  u += 0x7fffu + ((u >> 16) & 1u);
  return (unsigned short)(u >> 16);
}
__device__ __forceinline__ float bf2f(unsigned short h) {
  return __uint_as_float(((unsigned)h) << 16);
}
// RNE pack via the header API (compiler-visible; NOT inline asm).
__device__ __forceinline__ unsigned pack2(float a, float b) {
  __hip_bfloat162 h2 = __float22bfloat162_rn(float2{a, b});
  union { __hip_bfloat162 h; unsigned u; } cv;
  cv.h = h2;
  return cv.u;
}
__device__ __forceinline__ float fexp2(float x) {
#if __has_builtin(__builtin_amdgcn_exp2f)
  return __builtin_amdgcn_exp2f(x);
#else
  return exp2f(x);
#endif
}
__device__ __forceinline__ void split4(float4 v, uint2& hp, uint2& lp) {
  unsigned short h0 = f2bf(v.x), h1 = f2bf(v.y), h2 = f2bf(v.z), h3 = f2bf(v.w);
  unsigned short l0 = f2bf(v.x - bf2f(h0)), l1 = f2bf(v.y - bf2f(h1));
  unsigned short l2 = f2bf(v.z - bf2f(h2)), l3 = f2bf(v.w - bf2f(h3));
  hp.x = (unsigned)h0 | ((unsigned)h1 << 16);
  hp.y = (unsigned)h2 | ((unsigned)h3 << 16);
  lp.x = (unsigned)l0 | ((unsigned)l1 << 16);
  lp.y = (unsigned)l2 | ((unsigned)l3 << 16);
}

// ---------------------------------------------------------------------------
// P: merged prep — x-split | W-split | wproj-split | conv-weight prep
// ---------------------------------------------------------------------------
__global__ __launch_bounds__(256) void k_prep_all(
    const float* __restrict__ x, const float* __restrict__ wq,
    const float* __restrict__ wkv, const float* __restrict__ wres,
    const float* __restrict__ wproj, const float* __restrict__ k3,
    const float* __restrict__ k5, const float* __restrict__ k7,
    unsigned short* __restrict__ xhi, unsigned short* __restrict__ xlo,
    unsigned short* __restrict__ Whi, unsigned short* __restrict__ Wlo,
    unsigned short* __restrict__ pwhi, unsigned short* __restrict__ pwlo,
    unsigned short* __restrict__ wT) {
  int bx = blockIdx.x;
  int tid = threadIdx.x;
  if (bx < 2304) {
    int i = bx * 256 + tid;
    uint2 hp, lp;
    split4(((const float4*)x)[i], hp, lp);
    ((uint2*)xhi)[i] = hp;
    ((uint2*)xlo)[i] = lp;
  } else if (bx < 2560) {
    int idx = (bx - 2304) * 256 + tid;
    int row = idx >> 6, q4 = idx & 63;
    const float* src;
    if (row < 256)      src = wq + (size_t)row * 256;
    else if (row < 768) src = wkv + (size_t)(row - 256) * 256;
    else                src = wres + (size_t)(row - 768) * 256;
    uint2 hp, lp;
    split4(*(const float4*)(src + q4 * 4), hp, lp);
    ((uint2*)Whi)[idx] = hp;
    ((uint2*)Wlo)[idx] = lp;
  } else if (bx < 2624) {
    int idx = (bx - 2560) * 256 + tid;
    uint2 hp, lp;
    split4(((const float4*)wproj)[idx], hp, lp);
    ((uint2*)pwhi)[idx] = hp;
    ((uint2*)pwlo)[idx] = lp;
  } else {
    int idx = (bx - 2624) * 256 + tid;   // [0, 83*4096)
    const float* src; int K, tloc;
    if (idx < 9 * 4096)       { K = 3; src = k3; tloc = idx >> 12; }
    else if (idx < 34 * 4096) { K = 5; src = k5; tloc = (idx - 9 * 4096) >> 12; }
    else                      { K = 7; src = k7; tloc = (idx - 34 * 4096) >> 12; }
    int r = idx & 4095, oc = r >> 6, ic = r & 63;
    int K2 = K * K, ctr = K2 / 2;
    float v = (tloc == ctr) ? -1.f
            : src[((size_t)oc * 64 + ic) * (K2 - 1) + (tloc < ctr ? tloc : tloc - 1)];
    wT[idx] = f2bf(v);
  }
}

// ---------------------------------------------------------------------------
// K1: MFMA split-bf16 fused GEMM (unchanged)
// ---------------------------------------------------------------------------
__global__ __launch_bounds__(512, 2) void k_gemm_qkvres_mfma(
    const unsigned short* __restrict__ xhi, const unsigned short* __restrict__ xlo,
    const unsigned short* __restrict__ Whi, const unsigned short* __restrict__ Wlo,
    float* __restrict__ qb, unsigned short* __restrict__ khi,
    unsigned short* __restrict__ klo, unsigned short* __restrict__ vT,
    float* __restrict__ resb, unsigned short* __restrict__ resT) {
  __shared__ __align__(16) unsigned short Ah[128 * 64];
  __shared__ __align__(16) unsigned short Al[128 * 64];
  __shared__ __align__(16) unsigned short Bh[128 * 64];
  __shared__ __align__(16) unsigned short Bl[128 * 64];
  const int tid = threadIdx.x;
  const int row0 = blockIdx.x * 128;
  const int col0 = blockIdx.y * 128;
  const int w = tid >> 6, lane = tid & 63, lg = lane >> 4, lc = lane & 15;
  const int wm = w >> 1, wn = w & 1;

  f32x4 acc[2][4];
#pragma unroll
  for (int i = 0; i < 2; ++i)
#pragma unroll
    for (int j = 0; j < 4; ++j) acc[i][j] = (f32x4){0.f, 0.f, 0.f, 0.f};

  for (int kc = 0; kc < 256; kc += 64) {
    __syncthreads();
#pragma unroll
    for (int l = 0; l < 2; ++l) {
      int idx = tid + l * 512;
      int r = idx >> 3, o = idx & 7;
      int sl = ((o ^ (r & 7))) * 8;
      *(uint4*)&Ah[r * 64 + sl] = *(const uint4*)&xhi[(size_t)(row0 + r) * 256 + kc + o * 8];
      *(uint4*)&Al[r * 64 + sl] = *(const uint4*)&xlo[(size_t)(row0 + r) * 256 + kc + o * 8];
      *(uint4*)&Bh[r * 64 + sl] = *(const uint4*)&Whi[(size_t)(col0 + r) * 256 + kc + o * 8];
      *(uint4*)&Bl[r * 64 + sl] = *(const uint4*)&Wlo[(size_t)(col0 + r) * 256 + kc + o * 8];
    }
    __syncthreads();
#pragma unroll
    for (int ks = 0; ks < 2; ++ks) {
      short8 ah[2], al[2], bh[4], bl[4];
#pragma unroll
      for (int mi = 0; mi < 2; ++mi) {
        int r = wm * 32 + mi * 16 + lc;
        int sl = (((ks * 4 + lg) ^ (r & 7))) * 8;
        ah[mi] = *(short8*)&Ah[r * 64 + sl];
        al[mi] = *(short8*)&Al[r * 64 + sl];
      }
#pragma unroll
      for (int ni = 0; ni < 4; ++ni) {
        int r = wn * 64 + ni * 16 + lc;
        int sl = (((ks * 4 + lg) ^ (r & 7))) * 8;
        bh[ni] = *(short8*)&Bh[r * 64 + sl];
        bl[ni] = *(short8*)&Bl[r * 64 + sl];
      }
#pragma unroll
      for (int mi = 0; mi < 2; ++mi)
#pragma unroll
        for (int ni = 0; ni < 4; ++ni) {
          acc[mi][ni] = __builtin_amdgcn_mfma_f32_16x16x32_bf16(ah[mi], bh[ni], acc[mi][ni], 0, 0, 0);
          acc[mi][ni] = __builtin_amdgcn_mfma_f32_16x16x32_bf16(ah[mi], bl[ni], acc[mi][ni], 0, 0, 0);
          acc[mi][ni] = __builtin_amdgcn_mfma_f32_16x16x32_bf16(al[mi], bh[ni], acc[mi][ni], 0, 0, 0);
        }
    }
  }

#pragma unroll
  for (int mi = 0; mi < 2; ++mi) {
    int rbase = row0 + wm * 32 + mi * 16 + lg * 4;
#pragma unroll
    for (int ni = 0; ni < 4; ++ni) {
      int col = col0 + wn * 64 + ni * 16 + lc;
#pragma unroll
      for (int j = 0; j < 4; ++j) {
        int row = rbase + j;
        int b = row / NTOK, n = row % NTOK;
        float vv = acc[mi][ni][j];
        if (col < 256) {
          int head = col >> 5, ch = col & 31;
          qb[(((size_t)b * 8 + head) * NTOK + n) * 32 + ch] = vv;
        } else if (col < 512) {
          int o = col - 256; int head = o >> 5, ch = o & 31;
          size_t idx = (((size_t)b * 8 + head) * NTOK + n) * 32 + ch;
          unsigned short h = f2bf(vv);
          khi[idx] = h;
          klo[idx] = f2bf(vv - bf2f(h));
        } else if (col < 768) {
          int o = col - 512; int head = o >> 5, ch = o & 31;
          vT[(((size_t)b * 8 + head) * 32 + ch) * NTOK + n] = f2bf(vv);
        } else {
          int c = col - 768;
          float rv = fmaxf(vv, 0.f);
          resb[((size_t)b * 256 + c) * NTOK + n] = rv;
          if (c >= 64) {
            int g = (c >> 6) - 1, ic = c & 63;
            resT[(((size_t)b * 3 + g) * NTOK + n) * 64 + ic] = f2bf(rv);
          }
        }
      }
    }
  }
}

// ---------------------------------------------------------------------------
// softmax + PV for one 16-row q-subtile (in-register P, shuffle A-frag)
// ---------------------------------------------------------------------------
__device__ __forceinline__ void softmax_pv(
    f32x4 (&s)[8], float& m_r, float& l_r, f32x4& o0, f32x4& o1,
    int lg, int lc, int srcA, unsigned short (*vs)[136]) {
  float mx[8];
#pragma unroll
  for (int nt = 0; nt < 8; ++nt)
    mx[nt] = fmaxf(fmaxf(s[nt][0], s[nt][1]), fmaxf(s[nt][2], s[nt][3]));
  float mloc = fmaxf(fmaxf(fmaxf(mx[0], mx[1]), fmaxf(mx[2], mx[3])),
                     fmaxf(fmaxf(mx[4], mx[5]), fmaxf(mx[6], mx[7])));

  if (__any(mloc > m_r + 8.f)) {
    float mt = mloc;
    mt = fmaxf(mt, __shfl_xor(mt, 16, 64));
    mt = fmaxf(mt, __shfl_xor(mt, 32, 64));
    float mn = fmaxf(m_r, mt);
    float corr = fexp2(m_r - mn);
    m_r = mn;
    l_r *= corr;
#pragma unroll
    for (int j = 0; j < 4; ++j) {
      float cj = __shfl(corr, lg * 4 + j, 64);
      o0[j] *= cj;
      o1[j] *= cj;
    }
  }

  float ls = 0.f;
#pragma unroll
  for (int nt = 0; nt < 8; ++nt)
#pragma unroll
    for (int j = 0; j < 4; ++j) {
      float p = fexp2(s[nt][j] - m_r);
      s[nt][j] = p;
      ls += p;
    }
  l_r += ls;

  unsigned W[8][2];
#pragma unroll
  for (int nt = 0; nt < 8; ++nt) {
    W[nt][0] = pack2(s[nt][0], s[nt][1]);
    W[nt][1] = pack2(s[nt][2], s[nt][3]);
  }

  __builtin_amdgcn_s_setprio(1);
#pragma unroll
  for (int h2 = 0; h2 < 4; ++h2) {
    unsigned v0 = (lg & 2) ? W[2 * h2 + 1][0] : W[2 * h2][0];
    unsigned v1 = (lg & 2) ? W[2 * h2 + 1][1] : W[2 * h2][1];
    union { unsigned u[4]; short8 v; } pa;
    pa.u[0] = (unsigned)__shfl((int)v0, srcA, 64);
    pa.u[1] = (unsigned)__shfl((int)v1, srcA, 64);
    pa.u[2] = (unsigned)__shfl((int)v0, srcA + 16, 64);
    pa.u[3] = (unsigned)__shfl((int)v1, srcA + 16, 64);
    short8 vf0 = *(short8*)&vs[lc][h2 * 32 + lg * 8];
    short8 vf1 = *(short8*)&vs[lc + 16][h2 * 32 + lg * 8];
    o0 = __builtin_amdgcn_mfma_f32_16x16x32_bf16(pa.v, vf0, o0, 0, 0, 0);
    o1 = __builtin_amdgcn_mfma_f32_16x16x32_bf16(pa.v, vf1, o1, 0, 0, 0);
  }
  __builtin_amdgcn_s_setprio(0);
}

// ---------------------------------------------------------------------------
// attn device body v9 — round-13 structure, but QK computed in three
// term-passes: (kh,qh)x8, (kh,ql)x8, then (klr,qh)x8 with all 8 K-lo
// fragments loaded up front -> 16 independent MFMAs cover their L2 latency.
// ---------------------------------------------------------------------------
__device__ __forceinline__ void attn_body(
    int bh, int qt, int tid,
    const float* __restrict__ qb, const unsigned short* __restrict__ khi,
    const unsigned short* __restrict__ klo, const unsigned short* __restrict__ vT,
    float* __restrict__ accb,
    unsigned short (*ks_hi)[40], unsigned short (*vs)[136]) {
  const int r0 = qt * 64;
  const int w = tid >> 6;
  const int lane = tid & 63;
  const int lg = lane >> 4;
  const int lc = lane & 15;

  const float scale = 0.17677669529663688f * 1.4426950408889634f;

  const float* qp = qb + (((size_t)bh * NTOK + r0 + w * 16 + lc) * 32 + lg * 8);
  float qf[8];
  *(float4*)&qf[0] = *(const float4*)qp;
  *(float4*)&qf[4] = *(const float4*)(qp + 4);
  short8 qh, ql;
#pragma unroll
  for (int i = 0; i < 8; ++i) {
    float v = qf[i] * scale;
    unsigned short h = f2bf(v);
    qh[i] = (short)h;
    ql[i] = (short)f2bf(v - bf2f(h));
  }

  float m_r = -1.0e30f;
  float l_r = 0.f;
  f32x4 o0 = {0.f, 0.f, 0.f, 0.f};
  f32x4 o1 = {0.f, 0.f, 0.f, 0.f};

  const int krow = tid >> 1, kseg = (tid & 1) * 16;
  const int vrow = tid >> 3, vseg = (tid & 7) * 16;

  const unsigned short* khs = khi + ((size_t)bh * NTOK + krow) * 32 + kseg;
  const unsigned short* vsrc = vT + ((size_t)bh * 32 + vrow) * NTOK + vseg;
  const unsigned short* klp = klo + ((size_t)bh * NTOK + lc) * 32 + lg * 8;

  uint4 ph0 = *(const uint4*)khs,  ph1 = *(const uint4*)(khs + 8);
  uint4 pv0 = *(const uint4*)vsrc, pv1 = *(const uint4*)(vsrc + 8);

  const int srcA = ((lg & 1) * 2) * 16 + lc;

  for (int kt = 0; kt < 18; ++kt) {
    const int kv0 = kt * 128;
    __syncthreads();
    *(uint4*)&ks_hi[krow][kseg]     = ph0;
    *(uint4*)&ks_hi[krow][kseg + 8] = ph1;
    *(uint4*)&vs[vrow][vseg]        = pv0;
    *(uint4*)&vs[vrow][vseg + 8]    = pv1;
    __syncthreads();

    if (kt < 17) {
      size_t ko = (size_t)(kt + 1) * 128 * 32;
      int vo = (kt + 1) * 128;
      ph0 = *(const uint4*)(khs + ko);  ph1 = *(const uint4*)(khs + ko + 8);
      pv0 = *(const uint4*)(vsrc + vo); pv1 = *(const uint4*)(vsrc + vo + 8);
    }

    // issue ALL K-lo fragment loads first; consumed only in pass 3
    short8 klr[8];
#pragma unroll
    for (int nt = 0; nt < 8; ++nt)
      klr[nt] = *(const short8*)(klp + (size_t)(kv0 + nt * 16) * 32);

    f32x4 s[8];
    __builtin_amdgcn_s_setprio(1);
    // pass 1: kh x qh  (no klr dependency)
#pragma unroll
    for (int nt = 0; nt < 8; ++nt) {
      short8 kh = *(short8*)&ks_hi[nt * 16 + lc][lg * 8];
      f32x4 a = {0.f, 0.f, 0.f, 0.f};
      s[nt] = __builtin_amdgcn_mfma_f32_16x16x32_bf16(kh, qh, a, 0, 0, 0);
    }
    // pass 2: kh x ql  (no klr dependency; covers klr L2 latency)
#pragma unroll
    for (int nt = 0; nt < 8; ++nt) {
      short8 kh = *(short8*)&ks_hi[nt * 16 + lc][lg * 8];
      s[nt] = __builtin_amdgcn_mfma_f32_16x16x32_bf16(kh, ql, s[nt], 0, 0, 0);
    }
    // pass 3: klr x qh
#pragma unroll
    for (int nt = 0; nt < 8; ++nt)
      s[nt] = __builtin_amdgcn_mfma_f32_16x16x32_bf16(klr[nt], qh, s[nt], 0, 0, 0);
    __builtin_amdgcn_s_setprio(0);

    softmax_pv(s, m_r, l_r, o0, o1, lg, lc, srcA, vs);
  }

  float lfull = l_r;
  lfull += __shfl_xor(lfull, 16, 64);
  lfull += __shfl_xor(lfull, 32, 64);

  float* op = accb + ((size_t)bh * NTOK + r0 + w * 16) * 32;
#pragma unroll
  for (int j = 0; j < 4; ++j) {
    float lj = __shfl(lfull, lg * 4 + j, 64);
    float inv = 1.f / lj;
    int r = lg * 4 + j;
    op[r * 32 + lc] = o0[j] * inv;
    op[r * 32 + lc + 16] = o1[j] * inv;
  }
}

// ---------------------------------------------------------------------------
// conv device body (round-11, verbatim): two 32-channel halves, [K][56][32].
// ---------------------------------------------------------------------------
template <int K>
__device__ __forceinline__ void conv_body(
    const unsigned short* __restrict__ plane,
    const unsigned short* __restrict__ wTg,
    float* __restrict__ outg,
    int y, int w, int lane, unsigned short* lds) {
  constexpr int P = K / 2;
  const int tid = w * 64 + lane;
  const int lg = lane >> 4, lc = lane & 15;
  const int oc0 = w * 16;

  uint4 zz = {0, 0, 0, 0};
  for (int i = tid; i < K * 224; i += 256) ((uint4*)lds)[i] = zz;
  __syncthreads();

  f32x4 acc[3];
  acc[0] = acc[1] = acc[2] = (f32x4){0.f, 0.f, 0.f, 0.f};

#pragma unroll
  for (int c = 0; c < 2; ++c) {
    for (int idx = tid; idx < K * 192; idx += 256) {
      int i = idx / 192, rem = idx % 192;
      int gx = rem >> 2, o = rem & 3;
      int gy = y + i - P;
      if ((unsigned)gy < 48u) {
        uint4 v = *(const uint4*)(plane + ((size_t)(gy * 48 + gx)) * 64 + c * 32 + o * 8);
        int slot = gx + P;
        *(uint4*)(lds + ((size_t)i * 56 + slot) * 32 + ((o ^ ((slot >> 1) & 3)) * 8)) = v;
      }
    }
    __syncthreads();

    for (int ky = 0; ky < K; ++ky) {
#pragma unroll
      for (int kx = 0; kx < K; ++kx) {
        const int tap = ky * K + kx;
        short8 aw = *(const short8*)(wTg + (size_t)tap * 4096 + (oc0 + lc) * 64 +
                                     c * 32 + lg * 8);
#pragma unroll
        for (int u = 0; u < 3; ++u) {
          int slot = u * 16 + lc + kx;
          short8 bv = *(short8*)(lds + ((size_t)(ky * 56 + slot)) * 32 +
                                 ((lg ^ ((slot >> 1) & 3)) * 8));
          acc[u] = __builtin_amdgcn_mfma_f32_16x16x32_bf16(aw, bv, acc[u], 0, 0, 0);
        }
      }
    }
    __syncthreads();
  }

#pragma unroll
  for (int u = 0; u < 3; ++u)
#pragma unroll
    for (int j = 0; j < 4; ++j)
      outg[(size_t)(oc0 + lg * 4 + j) * NTOK + y * 48 + u * 16 + lc] = acc[u][j];
}

// ---------------------------------------------------------------------------
// pool device body
// ---------------------------------------------------------------------------
__device__ __forceinline__ void pool_body(
    const float* __restrict__ resb, float* __restrict__ pooled,
    int task, int lane) {
  const int sArr[4] = {1, 2, 3, 6};
  int g = task >> 8, rem = task & 255;
  int b = rem >> 6, cc = rem & 63;
  int c = g * 64 + cc;
  int S = sArr[g];
  int WSZ = 48 / S, NPX = WSZ * WSZ;
  const float* src = resb + ((size_t)b * 256 + c) * NTOK;
  const float inv = 1.f / NPX;
  for (int w = 0; w < S * S; ++w) {
    int wy = w / S, wx = w % S;
    float sum = 0.f;
    for (int idx = lane; idx < NPX; idx += 64) {
      int yy = wy * WSZ + idx / WSZ;
      int xx = wx * WSZ + idx % WSZ;
      sum += src[yy * 48 + xx];
    }
#pragma unroll
    for (int msk = 1; msk < 64; msk <<= 1) sum += __shfl_xor(sum, msk, 64);
    if (lane == 0) pooled[((size_t)b * 256 + c) * 36 + w] = sum * inv;
  }
}

// ---------------------------------------------------------------------------
// K2: FAT kernel — attn [0,1152) | conv [1152,1728) | pool [1728,1984)
// ---------------------------------------------------------------------------
__global__ __launch_bounds__(256, 4) void k_fat(
    const float* __restrict__ qb, const unsigned short* __restrict__ khi,
    const unsigned short* __restrict__ klo, const unsigned short* __restrict__ vT,
    float* __restrict__ accb, const unsigned short* __restrict__ resT,
    const unsigned short* __restrict__ wT, float* __restrict__ convb,
    const float* __restrict__ resb, float* __restrict__ pooled) {
  __shared__ __align__(16) unsigned char smem[25088];
  const int bx = blockIdx.x;
  const int tid = threadIdx.x;
  if (bx < 1152) {
    unsigned short (*ks_hi)[40] = (unsigned short(*)[40])(smem);
    unsigned short (*vs)[136]   = (unsigned short(*)[136])(smem + 10240);
    attn_body(bx & 31, bx >> 5, tid, qb, khi, klo, vT, accb, ks_hi, vs);
  } else if (bx < 1728) {
    int cid = bx - 1152;
    int g = cid % 3, rest = cid / 3;
    int b = rest / 48, y = rest % 48;
    const unsigned short* plane = resT + (((size_t)b * 3 + g) * NTOK) * 64;
    float* outg = convb + ((size_t)b * 192 + g * 64) * NTOK;
    unsigned short* lds = (unsigned short*)smem;
    int w = tid >> 6, lane = tid & 63;
    if (g == 0)      conv_body<3>(plane, wT,             outg, y, w, lane, lds);
    else if (g == 1) conv_body<5>(plane, wT + 9 * 4096,  outg, y, w, lane, lds);
    else             conv_body<7>(plane, wT + 34 * 4096, outg, y, w, lane, lds);
  } else {
    int task = (bx - 1728) * 4 + (tid >> 6);
    pool_body(resb, pooled, task, tid & 63);
  }
}

// ---------------------------------------------------------------------------
// K5: combine -> pre as bf16 hi/lo
// ---------------------------------------------------------------------------
__global__ void k_combine(
    const float* __restrict__ qb, const float* __restrict__ accb,
    const float* __restrict__ resb, const float* __restrict__ convb,
    const float* __restrict__ pooled, unsigned short* __restrict__ preh,
    unsigned short* __restrict__ prel) {
  int nt = blockIdx.x;
  int head = blockIdx.y;
  int b = blockIdx.z;
  int tid = threadIdx.x;
  int n = nt * 8 + (tid >> 5);
  int ch = tid & 31;
  int c = head * 32 + ch;
  int g = c >> 6;
  const int sArr[4] = {1, 2, 3, 6};
  int s = sArr[g];

  size_t qidx = (((size_t)b * 8 + head) * NTOK + n) * 32 + ch;
  float qv = qb[qidx];
  float av = accb[qidx];
  float cvv = (g == 0) ? resb[((size_t)b * 256 + c) * NTOK + n]
                       : convb[((size_t)b * 192 + (c - 64)) * NTOK + n];
  const float* pl = pooled + ((size_t)b * 256 + c) * 36;
  float lp;
  if (s == 1) {
    lp = pl[0];
  } else {
    int yy = n / 48, xx = n % 48;
    float fs = (float)(s - 1) / 47.0f;
    float ry = yy * fs, rx = xx * fs;
    int y0 = (int)ry, x0 = (int)rx;
    int y1 = min(y0 + 1, s - 1), x1 = min(x0 + 1, s - 1);
    float wy = ry - (float)y0, wx = rx - (float)x0;
    float v00 = pl[y0 * s + x0], v01 = pl[y0 * s + x1];
    float v10 = pl[y1 * s + x0], v11 = pl[y1 * s + x1];
    lp = v00 * (1 - wy) * (1 - wx) + v01 * (1 - wy) * wx +
         v10 * wy * (1 - wx) + v11 * wy * wx;
  }
  lp = fmaxf(lp, 0.f);
  float val = av + qv * cvv + lp;
  unsigned short h = f2bf(val);
  size_t oidx = ((size_t)b * NTOK + n) * 256 + c;
  preh[oidx] = h;
  prel[oidx] = f2bf(val - bf2f(h));
}

// ---------------------------------------------------------------------------
// K6: MFMA split-bf16 projection GEMM — BM=64 x BN=128 tiles, grid (144,2)
// ---------------------------------------------------------------------------
__global__ __launch_bounds__(512, 2) void k_gemm_proj_mfma(
    const unsigned short* __restrict__ preh, const unsigned short* __restrict__ prel,
    const unsigned short* __restrict__ pwhi, const unsigned short* __restrict__ pwlo,
    const float* __restrict__ bproj, float* __restrict__ outp) {
  __shared__ __align__(16) unsigned short Ah[64 * 64];
  __shared__ __align__(16) unsigned short Al[64 * 64];
  __shared__ __align__(16) unsigned short Bh[128 * 64];
  __shared__ __align__(16) unsigned short Bl[128 * 64];
  const int tid = threadIdx.x;
  const int row0 = blockIdx.x * 64;
  const int col0 = blockIdx.y * 128;
  const int w = tid >> 6, lane = tid & 63, lg = lane >> 4, lc = lane & 15;
  const int wm = w >> 2, wn = w & 3;

  f32x4 acc[2][2];
#pragma unroll
  for (int i = 0; i < 2; ++i)
#pragma unroll
    for (int j = 0; j < 2; ++j) acc[i][j] = (f32x4){0.f, 0.f, 0.f, 0.f};

  for (int kc = 0; kc < 256; kc += 64) {
    __syncthreads();
    {
      int r = tid >> 3, o = tid & 7;
      int sl = ((o ^ (r & 7))) * 8;
      *(uint4*)&Ah[r * 64 + sl] = *(const uint4*)&preh[(size_t)(row0 + r) * 256 + kc + o * 8];
      *(uint4*)&Al[r * 64 + sl] = *(const uint4*)&prel[(size_t)(row0 + r) * 256 + kc + o * 8];
    }
#pragma unroll
    for (int l = 0; l < 2; ++l) {
      int idx = tid + l * 512;
      int r = idx >> 3, o = idx & 7;
      int sl = ((o ^ (r & 7))) * 8;
      *(uint4*)&Bh[r * 64 + sl] = *(const uint4*)&pwhi[(size_t)(col0 + r) * 256 + kc + o * 8];
      *(uint4*)&Bl[r * 64 + sl] = *(const uint4*)&pwlo[(size_t)(col0 + r) * 256 + kc + o * 8];
    }
    __syncthreads();
#pragma unroll
    for (int ks = 0; ks < 2; ++ks) {
      short8 ah[2], al[2], bh[2], bl[2];
#pragma unroll
      for (int mi = 0; mi < 2; ++mi) {
        int r = wm * 32 + mi * 16 + lc;
        int sl = (((ks * 4 + lg) ^ (r & 7))) * 8;
        ah[mi] = *(short8*)&Ah[r * 64 + sl];
        al[mi] = *(short8*)&Al[r * 64 + sl];
      }
#pragma unroll
      for (int ni = 0; ni < 2; ++ni) {
        int r = wn * 32 + ni * 16 + lc;
        int sl = (((ks * 4 + lg) ^ (r & 7))) * 8;
        bh[ni] = *(short8*)&Bh[r * 64 + sl];
        bl[ni] = *(short8*)&Bl[r * 64 + sl];
      }
#pragma unroll
      for (int mi = 0; mi < 2; ++mi)
#pragma unroll
        for (int ni = 0; ni < 2; ++ni) {
          acc[mi][ni] = __builtin_amdgcn_mfma_f32_16x16x32_bf16(ah[mi], bh[ni], acc[mi][ni], 0, 0, 0);
          acc[mi][ni] = __builtin_amdgcn_mfma_f32_16x16x32_bf16(ah[mi], bl[ni], acc[mi][ni], 0, 0, 0);
          acc[mi][ni] = __builtin_amdgcn_mfma_f32_16x16x32_bf16(al[mi], bh[ni], acc[mi][ni], 0, 0, 0);
        }
    }
  }

#pragma unroll
  for (int mi = 0; mi < 2; ++mi) {
    int rbase = row0 + wm * 32 + mi * 16 + lg * 4;
#pragma unroll
    for (int ni = 0; ni < 2; ++ni) {
      int col = col0 + wn * 32 + ni * 16 + lc;
#pragma unroll
      for (int j = 0; j < 4; ++j)
        outp[(size_t)(rbase + j) * 256 + col] = acc[mi][ni][j] + bproj[col];
    }
  }
}

// ---------------------------------------------------------------------------
extern "C" void kernel_launch(void* const* d_in, const int* in_sizes, int n_in,
                              void* d_out, int out_size, void* d_ws, size_t ws_size,
                              hipStream_t stream) {
  const float* x     = (const float*)d_in[0];
  const float* wq    = (const float*)d_in[3];
  const float* wkv   = (const float*)d_in[4];
  const float* wres  = (const float*)d_in[5];
  const float* wproj = (const float*)d_in[6];
  const float* bproj = (const float*)d_in[7];
  const float* kern3 = (const float*)d_in[8];
  const float* kern5 = (const float*)d_in[9];
  const float* kern7 = (const float*)d_in[10];

  const size_t SZ = (size_t)4 * 8 * NTOK * 32;   // 2,359,296
  float* wsf  = (float*)d_ws;
  float* qb   = wsf;                                        // [0, SZ)
  float* resb = wsf + SZ;                                   // [SZ, 2SZ)
  float* accb = wsf + 2 * SZ;                               // [2SZ, 3SZ)
  unsigned short* xhi = (unsigned short*)(wsf + 2 * SZ);    // overlay accb
  unsigned short* xlo = (unsigned short*)(wsf + 2 * SZ + SZ / 2);
  unsigned short* khi = (unsigned short*)(wsf + 3 * SZ);
  unsigned short* klo = (unsigned short*)(wsf + 3 * SZ + SZ / 2);
  unsigned short* vT  = (unsigned short*)(wsf + 4 * SZ);
  unsigned short* resT = (unsigned short*)(wsf + 4 * SZ + SZ / 2);
  unsigned short* wT   = (unsigned short*)(wsf + 4 * SZ + SZ / 2 + 884736);
  unsigned short* Whi = (unsigned short*)(wsf + 4 * SZ + SZ / 2 + 884736 + 169984);
  unsigned short* Wlo = Whi + 262144;                       // dead after qkvres
  unsigned short* preh = (unsigned short*)(wsf + 4 * SZ + SZ / 2);  // overlay resT+
  unsigned short* prel = (unsigned short*)(wsf + 5 * SZ);
  float* convb  = wsf + SZ * 11 / 2;                        // 1,769,472 floats
  float* pooled = convb + 1769472;                          // 36,864 floats
  unsigned short* pwhi = (unsigned short*)(pooled + 36864); // 65,536 us
  unsigned short* pwlo = pwhi + 65536;                      // 65,536 us
  float* outp = (float*)d_out;

  k_prep_all<<<dim3(3952), 256, 0, stream>>>(x, wq, wkv, wres, wproj, kern3,
                                             kern5, kern7, xhi, xlo, Whi, Wlo,
                                             pwhi, pwlo, wT);
  k_gemm_qkvres_mfma<<<dim3(72, 8), 512, 0, stream>>>(xhi, xlo, Whi, Wlo, qb, khi,
                                                      klo, vT, resb, resT);
  k_fat<<<dim3(1984), 256, 0, stream>>>(qb, khi, klo, vT, accb, resT, wT, convb,
                                        resb, pooled);
  k_combine<<<dim3(288, 8, 4), 256, 0, stream>>>(qb, accb, resb, convb, pooled,
                                                 preh, prel);
  k_gemm_proj_mfma<<<dim3(144, 2), 512, 0, stream>>>(preh, prel, pwhi, pwlo, bproj, outp);
}

// Round 20
// 166.695 us; speedup vs baseline: 1.4336x; 1.4336x over previous
//
#include <hip/hip_runtime.h>
#include <hip/hip_bf16.h>
#include <math.h>

#define NTOK 2304   // N = 48*48
#define DIMC 256

typedef __attribute__((ext_vector_type(8))) short short8;
typedef __attribute__((ext_vector_type(4))) float f32x4;

__device__ __forceinline__ unsigned short f2bf(float f) {
  unsigned u = __float_as_uint(f);
  u += 0x7fffu + ((u >> 16) & 1u);
  return (unsigned short)(u >> 16);
}
__device__ __forceinline__ float bf2f(unsigned short h) {
  return __uint_as_float(((unsigned)h) << 16);
}
// RNE pack via the header API (compiler-visible; NOT inline asm).
__device__ __forceinline__ unsigned pack2(float a, float b) {
  __hip_bfloat162 h2 = __float22bfloat162_rn(float2{a, b});
  union { __hip_bfloat162 h; unsigned u; } cv;
  cv.h = h2;
  return cv.u;
}
__device__ __forceinline__ float fexp2(float x) {
#if __has_builtin(__builtin_amdgcn_exp2f)
  return __builtin_amdgcn_exp2f(x);
#else
  return exp2f(x);
#endif
}
__device__ __forceinline__ void split4(float4 v, uint2& hp, uint2& lp) {
  unsigned short h0 = f2bf(v.x), h1 = f2bf(v.y), h2 = f2bf(v.z), h3 = f2bf(v.w);
  unsigned short l0 = f2bf(v.x - bf2f(h0)), l1 = f2bf(v.y - bf2f(h1));
  unsigned short l2 = f2bf(v.z - bf2f(h2)), l3 = f2bf(v.w - bf2f(h3));
  hp.x = (unsigned)h0 | ((unsigned)h1 << 16);
  hp.y = (unsigned)h2 | ((unsigned)h3 << 16);
  lp.x = (unsigned)l0 | ((unsigned)l1 << 16);
  lp.y = (unsigned)l2 | ((unsigned)l3 << 16);
}

// ---------------------------------------------------------------------------
// P: merged prep — x-split | W-split | wproj-split | conv-weight prep
// ---------------------------------------------------------------------------
__global__ __launch_bounds__(256) void k_prep_all(
    const float* __restrict__ x, const float* __restrict__ wq,
    const float* __restrict__ wkv, const float* __restrict__ wres,
    const float* __restrict__ wproj, const float* __restrict__ k3,
    const float* __restrict__ k5, const float* __restrict__ k7,
    unsigned short* __restrict__ xhi, unsigned short* __restrict__ xlo,
    unsigned short* __restrict__ Whi, unsigned short* __restrict__ Wlo,
    unsigned short* __restrict__ pwhi, unsigned short* __restrict__ pwlo,
    unsigned short* __restrict__ wT) {
  int bx = blockIdx.x;
  int tid = threadIdx.x;
  if (bx < 2304) {
    int i = bx * 256 + tid;
    uint2 hp, lp;
    split4(((const float4*)x)[i], hp, lp);
    ((uint2*)xhi)[i] = hp;
    ((uint2*)xlo)[i] = lp;
  } else if (bx < 2560) {
    int idx = (bx - 2304) * 256 + tid;
    int row = idx >> 6, q4 = idx & 63;
    const float* src;
    if (row < 256)      src = wq + (size_t)row * 256;
    else if (row < 768) src = wkv + (size_t)(row - 256) * 256;
    else                src = wres + (size_t)(row - 768) * 256;
    uint2 hp, lp;
    split4(*(const float4*)(src + q4 * 4), hp, lp);
    ((uint2*)Whi)[idx] = hp;
    ((uint2*)Wlo)[idx] = lp;
  } else if (bx < 2624) {
    int idx = (bx - 2560) * 256 + tid;
    uint2 hp, lp;
    split4(((const float4*)wproj)[idx], hp, lp);
    ((uint2*)pwhi)[idx] = hp;
    ((uint2*)pwlo)[idx] = lp;
  } else {
    int idx = (bx - 2624) * 256 + tid;   // [0, 83*4096)
    const float* src; int K, tloc;
    if (idx < 9 * 4096)       { K = 3; src = k3; tloc = idx >> 12; }
    else if (idx < 34 * 4096) { K = 5; src = k5; tloc = (idx - 9 * 4096) >> 12; }
    else                      { K = 7; src = k7; tloc = (idx - 34 * 4096) >> 12; }
    int r = idx & 4095, oc = r >> 6, ic = r & 63;
    int K2 = K * K, ctr = K2 / 2;
    float v = (tloc == ctr) ? -1.f
            : src[((size_t)oc * 64 + ic) * (K2 - 1) + (tloc < ctr ? tloc : tloc - 1)];
    wT[idx] = f2bf(v);
  }
}

// ---------------------------------------------------------------------------
// K1: MFMA split-bf16 fused GEMM (unchanged)
// ---------------------------------------------------------------------------
__global__ __launch_bounds__(512, 2) void k_gemm_qkvres_mfma(
    const unsigned short* __restrict__ xhi, const unsigned short* __restrict__ xlo,
    const unsigned short* __restrict__ Whi, const unsigned short* __restrict__ Wlo,
    float* __restrict__ qb, unsigned short* __restrict__ khi,
    unsigned short* __restrict__ klo, unsigned short* __restrict__ vT,
    float* __restrict__ resb, unsigned short* __restrict__ resT) {
  __shared__ __align__(16) unsigned short Ah[128 * 64];
  __shared__ __align__(16) unsigned short Al[128 * 64];
  __shared__ __align__(16) unsigned short Bh[128 * 64];
  __shared__ __align__(16) unsigned short Bl[128 * 64];
  const int tid = threadIdx.x;
  const int row0 = blockIdx.x * 128;
  const int col0 = blockIdx.y * 128;
  const int w = tid >> 6, lane = tid & 63, lg = lane >> 4, lc = lane & 15;
  const int wm = w >> 1, wn = w & 1;

  f32x4 acc[2][4];
#pragma unroll
  for (int i = 0; i < 2; ++i)
#pragma unroll
    for (int j = 0; j < 4; ++j) acc[i][j] = (f32x4){0.f, 0.f, 0.f, 0.f};

  for (int kc = 0; kc < 256; kc += 64) {
    __syncthreads();
#pragma unroll
    for (int l = 0; l < 2; ++l) {
      int idx = tid + l * 512;
      int r = idx >> 3, o = idx & 7;
      int sl = ((o ^ (r & 7))) * 8;
      *(uint4*)&Ah[r * 64 + sl] = *(const uint4*)&xhi[(size_t)(row0 + r) * 256 + kc + o * 8];
      *(uint4*)&Al[r * 64 + sl] = *(const uint4*)&xlo[(size_t)(row0 + r) * 256 + kc + o * 8];
      *(uint4*)&Bh[r * 64 + sl] = *(const uint4*)&Whi[(size_t)(col0 + r) * 256 + kc + o * 8];
      *(uint4*)&Bl[r * 64 + sl] = *(const uint4*)&Wlo[(size_t)(col0 + r) * 256 + kc + o * 8];
    }
    __syncthreads();
#pragma unroll
    for (int ks = 0; ks < 2; ++ks) {
      short8 ah[2], al[2], bh[4], bl[4];
#pragma unroll
      for (int mi = 0; mi < 2; ++mi) {
        int r = wm * 32 + mi * 16 + lc;
        int sl = (((ks * 4 + lg) ^ (r & 7))) * 8;
        ah[mi] = *(short8*)&Ah[r * 64 + sl];
        al[mi] = *(short8*)&Al[r * 64 + sl];
      }
#pragma unroll
      for (int ni = 0; ni < 4; ++ni) {
        int r = wn * 64 + ni * 16 + lc;
        int sl = (((ks * 4 + lg) ^ (r & 7))) * 8;
        bh[ni] = *(short8*)&Bh[r * 64 + sl];
        bl[ni] = *(short8*)&Bl[r * 64 + sl];
      }
#pragma unroll
      for (int mi = 0; mi < 2; ++mi)
#pragma unroll
        for (int ni = 0; ni < 4; ++ni) {
          acc[mi][ni] = __builtin_amdgcn_mfma_f32_16x16x32_bf16(ah[mi], bh[ni], acc[mi][ni], 0, 0, 0);
          acc[mi][ni] = __builtin_amdgcn_mfma_f32_16x16x32_bf16(ah[mi], bl[ni], acc[mi][ni], 0, 0, 0);
          acc[mi][ni] = __builtin_amdgcn_mfma_f32_16x16x32_bf16(al[mi], bh[ni], acc[mi][ni], 0, 0, 0);
        }
    }
  }

#pragma unroll
  for (int mi = 0; mi < 2; ++mi) {
    int rbase = row0 + wm * 32 + mi * 16 + lg * 4;
#pragma unroll
    for (int ni = 0; ni < 4; ++ni) {
      int col = col0 + wn * 64 + ni * 16 + lc;
#pragma unroll
      for (int j = 0; j < 4; ++j) {
        int row = rbase + j;
        int b = row / NTOK, n = row % NTOK;
        float vv = acc[mi][ni][j];
        if (col < 256) {
          int head = col >> 5, ch = col & 31;
          qb[(((size_t)b * 8 + head) * NTOK + n) * 32 + ch] = vv;
        } else if (col < 512) {
          int o = col - 256; int head = o >> 5, ch = o & 31;
          size_t idx = (((size_t)b * 8 + head) * NTOK + n) * 32 + ch;
          unsigned short h = f2bf(vv);
          khi[idx] = h;
          klo[idx] = f2bf(vv - bf2f(h));
        } else if (col < 768) {
          int o = col - 512; int head = o >> 5, ch = o & 31;
          vT[(((size_t)b * 8 + head) * 32 + ch) * NTOK + n] = f2bf(vv);
        } else {
          int c = col - 768;
          float rv = fmaxf(vv, 0.f);
          resb[((size_t)b * 256 + c) * NTOK + n] = rv;
          if (c >= 64) {
            int g = (c >> 6) - 1, ic = c & 63;
            resT[(((size_t)b * 3 + g) * NTOK + n) * 64 + ic] = f2bf(rv);
          }
        }
      }
    }
  }
}

// ---------------------------------------------------------------------------
// softmax + PV for one 16-row q-subtile (in-register P, shuffle A-frag)
// pack2 via __float22bfloat162_rn (compiler-visible RNE pack).
// ---------------------------------------------------------------------------
__device__ __forceinline__ void softmax_pv(
    f32x4 (&s)[8], float& m_r, float& l_r, f32x4& o0, f32x4& o1,
    int lg, int lc, int srcA, unsigned short (*vs)[136]) {
  float mx[8];
#pragma unroll
  for (int nt = 0; nt < 8; ++nt)
    mx[nt] = fmaxf(fmaxf(s[nt][0], s[nt][1]), fmaxf(s[nt][2], s[nt][3]));
  float mloc = fmaxf(fmaxf(fmaxf(mx[0], mx[1]), fmaxf(mx[2], mx[3])),
                     fmaxf(fmaxf(mx[4], mx[5]), fmaxf(mx[6], mx[7])));

  if (__any(mloc > m_r + 8.f)) {
    float mt = mloc;
    mt = fmaxf(mt, __shfl_xor(mt, 16, 64));
    mt = fmaxf(mt, __shfl_xor(mt, 32, 64));
    float mn = fmaxf(m_r, mt);
    float corr = fexp2(m_r - mn);
    m_r = mn;
    l_r *= corr;
#pragma unroll
    for (int j = 0; j < 4; ++j) {
      float cj = __shfl(corr, lg * 4 + j, 64);
      o0[j] *= cj;
      o1[j] *= cj;
    }
  }

  float ls = 0.f;
#pragma unroll
  for (int nt = 0; nt < 8; ++nt)
#pragma unroll
    for (int j = 0; j < 4; ++j) {
      float p = fexp2(s[nt][j] - m_r);
      s[nt][j] = p;
      ls += p;
    }
  l_r += ls;

  unsigned W[8][2];
#pragma unroll
  for (int nt = 0; nt < 8; ++nt) {
    W[nt][0] = pack2(s[nt][0], s[nt][1]);
    W[nt][1] = pack2(s[nt][2], s[nt][3]);
  }

  __builtin_amdgcn_s_setprio(1);
#pragma unroll
  for (int h2 = 0; h2 < 4; ++h2) {
    unsigned v0 = (lg & 2) ? W[2 * h2 + 1][0] : W[2 * h2][0];
    unsigned v1 = (lg & 2) ? W[2 * h2 + 1][1] : W[2 * h2][1];
    union { unsigned u[4]; short8 v; } pa;
    pa.u[0] = (unsigned)__shfl((int)v0, srcA, 64);
    pa.u[1] = (unsigned)__shfl((int)v1, srcA, 64);
    pa.u[2] = (unsigned)__shfl((int)v0, srcA + 16, 64);
    pa.u[3] = (unsigned)__shfl((int)v1, srcA + 16, 64);
    short8 vf0 = *(short8*)&vs[lc][h2 * 32 + lg * 8];
    short8 vf1 = *(short8*)&vs[lc + 16][h2 * 32 + lg * 8];
    o0 = __builtin_amdgcn_mfma_f32_16x16x32_bf16(pa.v, vf0, o0, 0, 0, 0);
    o1 = __builtin_amdgcn_mfma_f32_16x16x32_bf16(pa.v, vf1, o1, 0, 0, 0);
  }
  __builtin_amdgcn_s_setprio(0);
}

// ---------------------------------------------------------------------------
// attn device body (round-13, verbatim): K-hi/V in LDS (tile-ahead reg
// prefetch), K-lo direct global->reg. LDS: ks_hi[128][40]+vs[32][136]=18944 B.
// ---------------------------------------------------------------------------
__device__ __forceinline__ void attn_body(
    int bh, int qt, int tid,
    const float* __restrict__ qb, const unsigned short* __restrict__ khi,
    const unsigned short* __restrict__ klo, const unsigned short* __restrict__ vT,
    float* __restrict__ accb,
    unsigned short (*ks_hi)[40], unsigned short (*vs)[136]) {
  const int r0 = qt * 64;
  const int w = tid >> 6;
  const int lane = tid & 63;
  const int lg = lane >> 4;
  const int lc = lane & 15;

  const float scale = 0.17677669529663688f * 1.4426950408889634f;

  const float* qp = qb + (((size_t)bh * NTOK + r0 + w * 16 + lc) * 32 + lg * 8);
  float qf[8];
  *(float4*)&qf[0] = *(const float4*)qp;
  *(float4*)&qf[4] = *(const float4*)(qp + 4);
  short8 qh, ql;
#pragma unroll
  for (int i = 0; i < 8; ++i) {
    float v = qf[i] * scale;
    unsigned short h = f2bf(v);
    qh[i] = (short)h;
    ql[i] = (short)f2bf(v - bf2f(h));
  }

  float m_r = -1.0e30f;
  float l_r = 0.f;
  f32x4 o0 = {0.f, 0.f, 0.f, 0.f};
  f32x4 o1 = {0.f, 0.f, 0.f, 0.f};

  const int krow = tid >> 1, kseg = (tid & 1) * 16;
  const int vrow = tid >> 3, vseg = (tid & 7) * 16;

  const unsigned short* khs = khi + ((size_t)bh * NTOK + krow) * 32 + kseg;
  const unsigned short* vsrc = vT + ((size_t)bh * 32 + vrow) * NTOK + vseg;
  const unsigned short* klp = klo + ((size_t)bh * NTOK + lc) * 32 + lg * 8;

  uint4 ph0 = *(const uint4*)khs,  ph1 = *(const uint4*)(khs + 8);
  uint4 pv0 = *(const uint4*)vsrc, pv1 = *(const uint4*)(vsrc + 8);

  const int srcA = ((lg & 1) * 2) * 16 + lc;

  for (int kt = 0; kt < 18; ++kt) {
    const int kv0 = kt * 128;
    __syncthreads();
    *(uint4*)&ks_hi[krow][kseg]     = ph0;
    *(uint4*)&ks_hi[krow][kseg + 8] = ph1;
    *(uint4*)&vs[vrow][vseg]        = pv0;
    *(uint4*)&vs[vrow][vseg + 8]    = pv1;
    __syncthreads();

    if (kt < 17) {
      size_t ko = (size_t)(kt + 1) * 128 * 32;
      int vo = (kt + 1) * 128;
      ph0 = *(const uint4*)(khs + ko);  ph1 = *(const uint4*)(khs + ko + 8);
      pv0 = *(const uint4*)(vsrc + vo); pv1 = *(const uint4*)(vsrc + vo + 8);
    }

    f32x4 s[8];
#pragma unroll
    for (int half = 0; half < 2; ++half) {
      short8 klr[4];
#pragma unroll
      for (int q = 0; q < 4; ++q)
        klr[q] = *(const short8*)(klp + (size_t)(kv0 + (half * 4 + q) * 16) * 32);
      __builtin_amdgcn_s_setprio(1);
#pragma unroll
      for (int q = 0; q < 4; ++q) {
        int nt = half * 4 + q;
        short8 kh = *(short8*)&ks_hi[nt * 16 + lc][lg * 8];
        f32x4 a = {0.f, 0.f, 0.f, 0.f};
        a = __builtin_amdgcn_mfma_f32_16x16x32_bf16(kh, qh, a, 0, 0, 0);
        a = __builtin_amdgcn_mfma_f32_16x16x32_bf16(klr[q], qh, a, 0, 0, 0);
        a = __builtin_amdgcn_mfma_f32_16x16x32_bf16(kh, ql, a, 0, 0, 0);
        s[nt] = a;
      }
      __builtin_amdgcn_s_setprio(0);
    }

    softmax_pv(s, m_r, l_r, o0, o1, lg, lc, srcA, vs);
  }

  float lfull = l_r;
  lfull += __shfl_xor(lfull, 16, 64);
  lfull += __shfl_xor(lfull, 32, 64);

  float* op = accb + ((size_t)bh * NTOK + r0 + w * 16) * 32;
#pragma unroll
  for (int j = 0; j < 4; ++j) {
    float lj = __shfl(lfull, lg * 4 + j, 64);
    float inv = 1.f / lj;
    int r = lg * 4 + j;
    op[r * 32 + lc] = o0[j] * inv;
    op[r * 32 + lc + 16] = o1[j] * inv;
  }
}

// ---------------------------------------------------------------------------
// conv device body (round-11, verbatim): two 32-channel halves, [K][56][32].
// ---------------------------------------------------------------------------
template <int K>
__device__ __forceinline__ void conv_body(
    const unsigned short* __restrict__ plane,
    const unsigned short* __restrict__ wTg,
    float* __restrict__ outg,
    int y, int w, int lane, unsigned short* lds) {
  constexpr int P = K / 2;
  const int tid = w * 64 + lane;
  const int lg = lane >> 4, lc = lane & 15;
  const int oc0 = w * 16;

  uint4 zz = {0, 0, 0, 0};
  for (int i = tid; i < K * 224; i += 256) ((uint4*)lds)[i] = zz;
  __syncthreads();

  f32x4 acc[3];
  acc[0] = acc[1] = acc[2] = (f32x4){0.f, 0.f, 0.f, 0.f};

#pragma unroll
  for (int c = 0; c < 2; ++c) {
    for (int idx = tid; idx < K * 192; idx += 256) {
      int i = idx / 192, rem = idx % 192;
      int gx = rem >> 2, o = rem & 3;
      int gy = y + i - P;
      if ((unsigned)gy < 48u) {
        uint4 v = *(const uint4*)(plane + ((size_t)(gy * 48 + gx)) * 64 + c * 32 + o * 8);
        int slot = gx + P;
        *(uint4*)(lds + ((size_t)i * 56 + slot) * 32 + ((o ^ ((slot >> 1) & 3)) * 8)) = v;
      }
    }
    __syncthreads();

    for (int ky = 0; ky < K; ++ky) {
#pragma unroll
      for (int kx = 0; kx < K; ++kx) {
        const int tap = ky * K + kx;
        short8 aw = *(const short8*)(wTg + (size_t)tap * 4096 + (oc0 + lc) * 64 +
                                     c * 32 + lg * 8);
#pragma unroll
        for (int u = 0; u < 3; ++u) {
          int slot = u * 16 + lc + kx;
          short8 bv = *(short8*)(lds + ((size_t)(ky * 56 + slot)) * 32 +
                                 ((lg ^ ((slot >> 1) & 3)) * 8));
          acc[u] = __builtin_amdgcn_mfma_f32_16x16x32_bf16(aw, bv, acc[u], 0, 0, 0);
        }
      }
    }
    __syncthreads();
  }

#pragma unroll
  for (int u = 0; u < 3; ++u)
#pragma unroll
    for (int j = 0; j < 4; ++j)
      outg[(size_t)(oc0 + lg * 4 + j) * NTOK + y * 48 + u * 16 + lc] = acc[u][j];
}

// ---------------------------------------------------------------------------
// pool device body
// ---------------------------------------------------------------------------
__device__ __forceinline__ void pool_body(
    const float* __restrict__ resb, float* __restrict__ pooled,
    int task, int lane) {
  const int sArr[4] = {1, 2, 3, 6};
  int g = task >> 8, rem = task & 255;
  int b = rem >> 6, cc = rem & 63;
  int c = g * 64 + cc;
  int S = sArr[g];
  int WSZ = 48 / S, NPX = WSZ * WSZ;
  const float* src = resb + ((size_t)b * 256 + c) * NTOK;
  const float inv = 1.f / NPX;
  for (int w = 0; w < S * S; ++w) {
    int wy = w / S, wx = w % S;
    float sum = 0.f;
    for (int idx = lane; idx < NPX; idx += 64) {
      int yy = wy * WSZ + idx / WSZ;
      int xx = wx * WSZ + idx % WSZ;
      sum += src[yy * 48 + xx];
    }
#pragma unroll
    for (int msk = 1; msk < 64; msk <<= 1) sum += __shfl_xor(sum, msk, 64);
    if (lane == 0) pooled[((size_t)b * 256 + c) * 36 + w] = sum * inv;
  }
}

// ---------------------------------------------------------------------------
// K2: FAT kernel — attn [0,1152) | conv [1152,1728) | pool [1728,1984)
// Shared 25088-byte smem: attn {ks_hi 10240 | vs 8704}, conv [K][56][32].
// ---------------------------------------------------------------------------
__global__ __launch_bounds__(256, 4) void k_fat(
    const float* __restrict__ qb, const unsigned short* __restrict__ khi,
    const unsigned short* __restrict__ klo, const unsigned short* __restrict__ vT,
    float* __restrict__ accb, const unsigned short* __restrict__ resT,
    const unsigned short* __restrict__ wT, float* __restrict__ convb,
    const float* __restrict__ resb, float* __restrict__ pooled) {
  __shared__ __align__(16) unsigned char smem[25088];
  const int bx = blockIdx.x;
  const int tid = threadIdx.x;
  if (bx < 1152) {
    unsigned short (*ks_hi)[40] = (unsigned short(*)[40])(smem);
    unsigned short (*vs)[136]   = (unsigned short(*)[136])(smem + 10240);
    attn_body(bx & 31, bx >> 5, tid, qb, khi, klo, vT, accb, ks_hi, vs);
  } else if (bx < 1728) {
    int cid = bx - 1152;
    int g = cid % 3, rest = cid / 3;
    int b = rest / 48, y = rest % 48;
    const unsigned short* plane = resT + (((size_t)b * 3 + g) * NTOK) * 64;
    float* outg = convb + ((size_t)b * 192 + g * 64) * NTOK;
    unsigned short* lds = (unsigned short*)smem;
    int w = tid >> 6, lane = tid & 63;
    if (g == 0)      conv_body<3>(plane, wT,             outg, y, w, lane, lds);
    else if (g == 1) conv_body<5>(plane, wT + 9 * 4096,  outg, y, w, lane, lds);
    else             conv_body<7>(plane, wT + 34 * 4096, outg, y, w, lane, lds);
  } else {
    int task = (bx - 1728) * 4 + (tid >> 6);
    pool_body(resb, pooled, task, tid & 63);
  }
}

// ---------------------------------------------------------------------------
// K5: combine -> pre as bf16 hi/lo
// ---------------------------------------------------------------------------
__global__ void k_combine(
    const float* __restrict__ qb, const float* __restrict__ accb,
    const float* __restrict__ resb, const float* __restrict__ convb,
    const float* __restrict__ pooled, unsigned short* __restrict__ preh,
    unsigned short* __restrict__ prel) {
  int nt = blockIdx.x;
  int head = blockIdx.y;
  int b = blockIdx.z;
  int tid = threadIdx.x;
  int n = nt * 8 + (tid >> 5);
  int ch = tid & 31;
  int c = head * 32 + ch;
  int g = c >> 6;
  const int sArr[4] = {1, 2, 3, 6};
  int s = sArr[g];

  size_t qidx = (((size_t)b * 8 + head) * NTOK + n) * 32 + ch;
  float qv = qb[qidx];
  float av = accb[qidx];
  float cvv = (g == 0) ? resb[((size_t)b * 256 + c) * NTOK + n]
                       : convb[((size_t)b * 192 + (c - 64)) * NTOK + n];
  const float* pl = pooled + ((size_t)b * 256 + c) * 36;
  float lp;
  if (s == 1) {
    lp = pl[0];
  } else {
    int yy = n / 48, xx = n % 48;
    float fs = (float)(s - 1) / 47.0f;
    float ry = yy * fs, rx = xx * fs;
    int y0 = (int)ry, x0 = (int)rx;
    int y1 = min(y0 + 1, s - 1), x1 = min(x0 + 1, s - 1);
    float wy = ry - (float)y0, wx = rx - (float)x0;
    float v00 = pl[y0 * s + x0], v01 = pl[y0 * s + x1];
    float v10 = pl[y1 * s + x0], v11 = pl[y1 * s + x1];
    lp = v00 * (1 - wy) * (1 - wx) + v01 * (1 - wy) * wx +
         v10 * wy * (1 - wx) + v11 * wy * wx;
  }
  lp = fmaxf(lp, 0.f);
  float val = av + qv * cvv + lp;
  unsigned short h = f2bf(val);
  size_t oidx = ((size_t)b * NTOK + n) * 256 + c;
  preh[oidx] = h;
  prel[oidx] = f2bf(val - bf2f(h));
}

// ---------------------------------------------------------------------------
// K6: MFMA split-bf16 projection GEMM — BM=64 x BN=128 tiles, grid (144,2)
// ---------------------------------------------------------------------------
__global__ __launch_bounds__(512, 2) void k_gemm_proj_mfma(
    const unsigned short* __restrict__ preh, const unsigned short* __restrict__ prel,
    const unsigned short* __restrict__ pwhi, const unsigned short* __restrict__ pwlo,
    const float* __restrict__ bproj, float* __restrict__ outp) {
  __shared__ __align__(16) unsigned short Ah[64 * 64];
  __shared__ __align__(16) unsigned short Al[64 * 64];
  __shared__ __align__(16) unsigned short Bh[128 * 64];
  __shared__ __align__(16) unsigned short Bl[128 * 64];
  const int tid = threadIdx.x;
  const int row0 = blockIdx.x * 64;
  const int col0 = blockIdx.y * 128;
  const int w = tid >> 6, lane = tid & 63, lg = lane >> 4, lc = lane & 15;
  const int wm = w >> 2, wn = w & 3;

  f32x4 acc[2][2];
#pragma unroll
  for (int i = 0; i < 2; ++i)
#pragma unroll
    for (int j = 0; j < 2; ++j) acc[i][j] = (f32x4){0.f, 0.f, 0.f, 0.f};

  for (int kc = 0; kc < 256; kc += 64) {
    __syncthreads();
    {
      int r = tid >> 3, o = tid & 7;
      int sl = ((o ^ (r & 7))) * 8;
      *(uint4*)&Ah[r * 64 + sl] = *(const uint4*)&preh[(size_t)(row0 + r) * 256 + kc + o * 8];
      *(uint4*)&Al[r * 64 + sl] = *(const uint4*)&prel[(size_t)(row0 + r) * 256 + kc + o * 8];
    }
#pragma unroll
    for (int l = 0; l < 2; ++l) {
      int idx = tid + l * 512;
      int r = idx >> 3, o = idx & 7;
      int sl = ((o ^ (r & 7))) * 8;
      *(uint4*)&Bh[r * 64 + sl] = *(const uint4*)&pwhi[(size_t)(col0 + r) * 256 + kc + o * 8];
      *(uint4*)&Bl[r * 64 + sl] = *(const uint4*)&pwlo[(size_t)(col0 + r) * 256 + kc + o * 8];
    }
    __syncthreads();
#pragma unroll
    for (int ks = 0; ks < 2; ++ks) {
      short8 ah[2], al[2], bh[2], bl[2];
#pragma unroll
      for (int mi = 0; mi < 2; ++mi) {
        int r = wm * 32 + mi * 16 + lc;
        int sl = (((ks * 4 + lg) ^ (r & 7))) * 8;
        ah[mi] = *(short8*)&Ah[r * 64 + sl];
        al[mi] = *(short8*)&Al[r * 64 + sl];
      }
#pragma unroll
      for (int ni = 0; ni < 2; ++ni) {
        int r = wn * 32 + ni * 16 + lc;
        int sl = (((ks * 4 + lg) ^ (r & 7))) * 8;
        bh[ni] = *(short8*)&Bh[r * 64 + sl];
        bl[ni] = *(short8*)&Bl[r * 64 + sl];
      }
#pragma unroll
      for (int mi = 0; mi < 2; ++mi)
#pragma unroll
        for (int ni = 0; ni < 2; ++ni) {
          acc[mi][ni] = __builtin_amdgcn_mfma_f32_16x16x32_bf16(ah[mi], bh[ni], acc[mi][ni], 0, 0, 0);
          acc[mi][ni] = __builtin_amdgcn_mfma_f32_16x16x32_bf16(ah[mi], bl[ni], acc[mi][ni], 0, 0, 0);
          acc[mi][ni] = __builtin_amdgcn_mfma_f32_16x16x32_bf16(al[mi], bh[ni], acc[mi][ni], 0, 0, 0);
        }
    }
  }

#pragma unroll
  for (int mi = 0; mi < 2; ++mi) {
    int rbase = row0 + wm * 32 + mi * 16 + lg * 4;
#pragma unroll
    for (int ni = 0; ni < 2; ++ni) {
      int col = col0 + wn * 32 + ni * 16 + lc;
#pragma unroll
      for (int j = 0; j < 4; ++j)
        outp[(size_t)(rbase + j) * 256 + col] = acc[mi][ni][j] + bproj[col];
    }
  }
}

// ---------------------------------------------------------------------------
extern "C" void kernel_launch(void* const* d_in, const int* in_sizes, int n_in,
                              void* d_out, int out_size, void* d_ws, size_t ws_size,
                              hipStream_t stream) {
  const float* x     = (const float*)d_in[0];
  const float* wq    = (const float*)d_in[3];
  const float* wkv   = (const float*)d_in[4];
  const float* wres  = (const float*)d_in[5];
  const float* wproj = (const float*)d_in[6];
  const float* bproj = (const float*)d_in[7];
  const float* kern3 = (const float*)d_in[8];
  const float* kern5 = (const float*)d_in[9];
  const float* kern7 = (const float*)d_in[10];

  const size_t SZ = (size_t)4 * 8 * NTOK * 32;   // 2,359,296
  float* wsf  = (float*)d_ws;
  float* qb   = wsf;                                        // [0, SZ)
  float* resb = wsf + SZ;                                   // [SZ, 2SZ)
  float* accb = wsf + 2 * SZ;                               // [2SZ, 3SZ)
  unsigned short* xhi = (unsigned short*)(wsf + 2 * SZ);    // overlay accb
  unsigned short* xlo = (unsigned short*)(wsf + 2 * SZ + SZ / 2);
  unsigned short* khi = (unsigned short*)(wsf + 3 * SZ);
  unsigned short* klo = (unsigned short*)(wsf + 3 * SZ + SZ / 2);
  unsigned short* vT  = (unsigned short*)(wsf + 4 * SZ);
  unsigned short* resT = (unsigned short*)(wsf + 4 * SZ + SZ / 2);
  unsigned short* wT   = (unsigned short*)(wsf + 4 * SZ + SZ / 2 + 884736);
  unsigned short* Whi = (unsigned short*)(wsf + 4 * SZ + SZ / 2 + 884736 + 169984);
  unsigned short* Wlo = Whi + 262144;                       // dead after qkvres
  unsigned short* preh = (unsigned short*)(wsf + 4 * SZ + SZ / 2);  // overlay resT+
  unsigned short* prel = (unsigned short*)(wsf + 5 * SZ);
  float* convb  = wsf + SZ * 11 / 2;                        // 1,769,472 floats
  float* pooled = convb + 1769472;                          // 36,864 floats
  unsigned short* pwhi = (unsigned short*)(pooled + 36864); // 65,536 us
  unsigned short* pwlo = pwhi + 65536;                      // 65,536 us
  float* outp = (float*)d_out;

  k_prep_all<<<dim3(3952), 256, 0, stream>>>(x, wq, wkv, wres, wproj, kern3,
                                             kern5, kern7, xhi, xlo, Whi, Wlo,
                                             pwhi, pwlo, wT);
  k_gemm_qkvres_mfma<<<dim3(72, 8), 512, 0, stream>>>(xhi, xlo, Whi, Wlo, qb, khi,
                                                      klo, vT, resb, resT);
  k_fat<<<dim3(1984), 256, 0, stream>>>(qb, khi, klo, vT, accb, resT, wT, convb,
                                        resb, pooled);
  k_combine<<<dim3(288, 8, 4), 256, 0, stream>>>(qb, accb, resb, convb, pooled,
                                                 preh, prel);
  k_gemm_proj_mfma<<<dim3(144, 2), 512, 0, stream>>>(preh, prel, pwhi, pwlo, bproj, outp);
}